// Round 7
// baseline (202.731 us; speedup 1.0000x reference)
//
#include <hip/hip_runtime.h>
#include <hip/hip_bf16.h>

// Problem constants
constexpr int B = 4, C = 64, H = 192, W = 192;
constexpr int HEADS = 4, D = 16;           // d = C/HEADS
constexpr int BLK = 8, HALO = 3, WIN = 14; // WIN = BLK + 2*HALO
constexpr int NH = H / BLK, NW = W / BLK;  // 24 x 24 windows
constexpr int HW = H * W;                  // 36864
constexpr int O = 3 * C;                   // 192 qkv channels

// attn LDS layout (units: shorts) — V planes + rel tables only (no K plane)
constexpr int VPLANE = 208 * 16 + 16;      // V plane: [208 slots][16 ch] + pad
constexpr int V_OFF = 0;
constexpr int RH_OFF = 4 * VPLANE;         // rel_h bf16 [16][8] (rows >=14 clamped)
constexpr int RW_OFF = RH_OFF + 128;       // rel_w bf16 [16][8]
constexpr int LDS_TOT = RW_OFF + 128;      // 13632 shorts = 27264 B

typedef __attribute__((ext_vector_type(4))) short short4v;
typedef __attribute__((ext_vector_type(8))) short short8v;
typedef __attribute__((ext_vector_type(8))) __bf16 bf16x8;
typedef __attribute__((ext_vector_type(4))) float f32x4;

__device__ inline f32x4 mfma_bf16(short8v a, short8v b, f32x4 c) {
  return __builtin_amdgcn_mfma_f32_16x16x32_bf16(
      __builtin_bit_cast(bf16x8, a), __builtin_bit_cast(bf16x8, b), c, 0, 0, 0);
}

__device__ inline unsigned short f2bf(float f) {
  __bf16 h = (__bf16)f;
  return __builtin_bit_cast(unsigned short, h);
}

// ---------------------------------------------------------------------------
// Kernel 1: qkv projection as MFMA GEMM (unchanged; near HBM floor).
// q rows pre-scaled by d^-0.5 * log2(e) so attention works in exp2 domain.
// ---------------------------------------------------------------------------
__global__ __launch_bounds__(256) void qkv_mfma(
    const float* __restrict__ x, const float* __restrict__ w,
    unsigned short* __restrict__ qkv) {
  __shared__ unsigned short wlds[192 * 64];
  const int tid = threadIdx.x;

  const float4* wf4 = reinterpret_cast<const float4*>(w);
#pragma unroll
  for (int it = 0; it < 12; ++it) {
    const int idx = it * 256 + tid;  // 3072 float4s
    const int o = idx >> 4;
    const int c = (idx & 15) << 2;
    const float4 wv = wf4[idx];
    ushort4 st;
    st.x = f2bf(wv.x);
    st.y = f2bf(wv.y);
    st.z = f2bf(wv.z);
    st.w = f2bf(wv.w);
    const int sw = (((c >> 3) ^ (o & 7)) << 3) + (c & 4);
    *reinterpret_cast<ushort4*>(&wlds[o * 64 + sw]) = st;
  }

  const int wave = tid >> 6, lane = tid & 63;
  const int p = lane & 15, g = lane >> 4;
  const int pix_w = blockIdx.x * 128 + wave * 32;
  const int b = pix_w / HW;
  const int hw = pix_w - b * HW + p;
  const float* xb = x + (size_t)b * C * HW;

  short8v xf[2][2];
#pragma unroll
  for (int pt = 0; pt < 2; ++pt) {
#pragma unroll
    for (int ks = 0; ks < 2; ++ks) {
      unsigned short u[8];
#pragma unroll
      for (int j = 0; j < 8; ++j)
        u[j] = f2bf(xb[(size_t)(ks * 32 + g * 8 + j) * HW + hw + pt * 16]);
      unsigned int pw[4];
#pragma unroll
      for (int e = 0; e < 4; ++e)
        pw[e] = (unsigned int)u[2 * e] | ((unsigned int)u[2 * e + 1] << 16);
      xf[pt][ks] = __builtin_bit_cast(short8v, *reinterpret_cast<uint4*>(pw));
    }
  }
  __syncthreads();

#pragma unroll
  for (int ot = 0; ot < 12; ++ot) {
    short8v af[2];
#pragma unroll
    for (int ks = 0; ks < 2; ++ks)
      af[ks] = *reinterpret_cast<const short8v*>(
          wlds + (ot * 16 + p) * 64 + (((((ks << 2) | g)) ^ (p & 7)) << 3));
    // q pre-scale: d^-0.5 * log2(e) -> attention uses exp2 directly
    const float s = (ot < 4) ? 0.25f * 1.44269504f : 1.0f;
#pragma unroll
    for (int pt = 0; pt < 2; ++pt) {
      f32x4 acc = {0.f, 0.f, 0.f, 0.f};
      acc = mfma_bf16(af[0], xf[pt][0], acc);
      acc = mfma_bf16(af[1], xf[pt][1], acc);
      ushort4 st;
      st.x = f2bf(acc[0] * s);
      st.y = f2bf(acc[1] * s);
      st.z = f2bf(acc[2] * s);
      st.w = f2bf(acc[3] * s);
      *reinterpret_cast<ushort4*>(
          qkv + (size_t)(pix_w + pt * 16 + p) * O + ot * 16 + g * 4) = st;
    }
  }
}

// ---------------------------------------------------------------------------
// Kernel 2: MFMA window attention v4.
// - No K-LDS: K fragments loaded straight from global per QK tile (each 16B
//   chunk has zero cross-thread reuse; halo region stays L1/L2-hot).
//   LDS 54.3KB -> 27.3KB, occupancy cap 24 -> 32 waves/CU.
// - No softmax max-pass: sim is O(1) in log2-domain, exp2 is fp32-safe;
//   p/sum is scale-invariant. Shorter dependency chain.
// - rel folded into MFMA spare depth (A 16-23 = rel_h, 24-31 = rel_w; B
//   carries q[0:8]/q[8:16] on hq>=2 lanes); V via ds_read_b64_tr_b16.
// ---------------------------------------------------------------------------
__global__ __launch_bounds__(512, 6) void attn_kernel(
    const unsigned short* __restrict__ qkv,
    const float* __restrict__ rel_h, const float* __restrict__ rel_w,
    float* __restrict__ out) {
  __shared__ __align__(16) unsigned short lds[LDS_TOT];

  const int tid = threadIdx.x;
  const int blk = blockIdx.x;
  const int win = (blk & 7) * 288 + (blk >> 3);  // XCD swizzle (2304 % 8 == 0)
  const int b = win / (NH * NW);
  const int wrem = win - b * (NH * NW);
  const int bh = wrem / NW;
  const int bw = wrem - bh * NW;
  const int y0 = bh * BLK - HALO;
  const int x0 = bw * BLK - HALO;

  // ---- rel tables -> bf16 LDS (rows >= 14 clamped to 13) ----
  if (tid < 256) {
    const int i = tid & 127;
    const int rr = i >> 3, cc = i & 7;
    const int rc = (rr < WIN) ? rr : (WIN - 1);
    const float* src = (tid < 128) ? rel_h : rel_w;
    lds[((tid < 128) ? RH_OFF : RW_OFF) + i] = f2bf(src[rc * 8 + cc]);
  }

  // ---- V staging phase 1: issue loads (1664 items = 208 pixels x 8 chunks) -
  uint4 raw[4];
#pragma unroll
  for (int it = 0; it < 4; ++it) {
    const int item = tid + it * 512;
    const int pixel = item >> 3;
    const int g = item & 7;
    const int wy = pixel / WIN;
    const int wx = pixel - wy * WIN;
    const int y = y0 + wy, xx = x0 + wx;
    const bool inb =
        (item < 1664) & (y >= 0) & (y < H) & (xx >= 0) & (xx < W);
    uint4 rv = make_uint4(0u, 0u, 0u, 0u);
    if (inb)
      rv = *reinterpret_cast<const uint4*>(
          qkv + ((size_t)(b * HW + y * W + xx)) * O + 2 * C + g * 8);
    raw[it] = rv;
  }

  // ---- Q fragment prefetch (hq>=2 lanes supply q[0:8]/q[8:16] for the rel
  //      depth slots) ----
  const int lane = tid & 63;
  const int wv = tid >> 6;
  const int head = wv & 3;
  const int qhalf = wv >> 2;
  const int r = lane & 15, hq = lane >> 4;
  short8v qf[2];
#pragma unroll
  for (int q2 = 0; q2 < 2; ++q2) {
    const int qrow = (qhalf * 2 + q2) * 16 + r;
    const int y = bh * BLK + (qrow >> 3);
    const int xx = bw * BLK + (qrow & 7);
    qf[q2] = *reinterpret_cast<const short8v*>(
        qkv + ((size_t)(b * HW + y * W + xx)) * O + head * D + (hq & 1) * 8);
  }

  // ---- V staging phase 2: LDS writes ----
#pragma unroll
  for (int it = 0; it < 4; ++it) {
    const int item = tid + it * 512;
    if (item < 1664) {
      const int pixel = item >> 3;
      const int g = item & 7;
      const int hd = g >> 1, c8 = g & 1;
      *reinterpret_cast<uint4*>(
          &lds[V_OFF + hd * VPLANE + pixel * 16 + c8 * 8]) = raw[it];
    }
  }
  __syncthreads();

  // ---- per-tile K global byte-offsets (hq<2) / rel LDS short-indices (hq>=2)
  // row = 16t + r -> (wy, wx) tracked incrementally; addresses clamped so OOB
  // lanes read valid memory, then zeroed via inbm bit (edge blocks only).
  const char* qkv_raw = reinterpret_cast<const char*>(qkv);
  const bool interior =
      (bh > 0) & (bh < NH - 1) & (bw > 0) & (bw < NW - 1);
  int koff[13];
  unsigned inbm = 0x1FFFu;
  {
    int wy = (r < WIN) ? 0 : 1;
    int wx = (r < WIN) ? r : r - WIN;
    if (!interior) {
      int wy2 = wy, wx2 = wx;
      unsigned mbits = 0;
#pragma unroll
      for (int t = 0; t < 13; ++t) {
        const int yy = y0 + wy2, xx2 = x0 + wx2;
        const bool ib = (yy >= 0) & (yy < H) & (xx2 >= 0) & (xx2 < W);
        mbits |= (ib ? 1u : 0u) << t;
        wx2 += 2;
        wy2 += 1;
        if (wx2 >= WIN) {
          wx2 -= WIN;
          wy2 += 1;
        }
      }
      inbm = mbits;
    }
#pragma unroll
    for (int t = 0; t < 13; ++t) {
      int yy = y0 + wy, xx2 = x0 + wx;
      yy = (yy < 0) ? 0 : ((yy > H - 1) ? H - 1 : yy);
      xx2 = (xx2 < 0) ? 0 : ((xx2 > W - 1) ? W - 1 : xx2);
      const int goff =
          ((b * HW + yy * W + xx2) * O + C + head * D + (hq & 1) * 8) * 2;
      const int roff = (hq == 2) ? (RH_OFF + wy * 8) : (RW_OFF + wx * 8);
      koff[t] = (hq < 2) ? goff : roff;
      wx += 2;
      wy += 1;
      if (wx >= WIN) {
        wx -= WIN;
        wy += 1;
      }
    }
  }

  const unsigned vbase_addr =
      (unsigned)(unsigned long long)(const void*)&lds[V_OFF + head * VPLANE] +
      (unsigned)(lane * 8);
  const short8v z8 = {0, 0, 0, 0, 0, 0, 0, 0};

  for (int q2 = 0; q2 < 2; ++q2) {
    // ---- sim^T tiles: augmented MFMA computes q*(k+rel) ----
    f32x4 sim[13];
#pragma unroll
    for (int t = 0; t < 13; ++t) {
      short8v kf;
      if (hq < 2) {
        kf = *reinterpret_cast<const short8v*>(qkv_raw + koff[t]);
        if (!((inbm >> t) & 1u)) kf = z8;  // folds away for interior blocks
      } else {
        kf = *reinterpret_cast<const short8v*>(&lds[koff[t]]);
      }
      f32x4 z4 = {0.f, 0.f, 0.f, 0.f};
      sim[t] = mfma_bf16(kf, qf[q2], z4);
    }

    // ---- softmax, no max-pass (log2-domain sims are O(1)) ----
    float sum = 0.f;
#pragma unroll
    for (int t = 0; t < 13; ++t) {
#pragma unroll
      for (int e = 0; e < 4; ++e) {
        float p = exp2f(sim[t][e]);
        if (t == 12 && hq >= 1) p = 0.f;  // keys >= 196: pad
        sim[t][e] = p;
        sum += p;
      }
    }
    sum += __shfl_xor(sum, 16);
    sum += __shfl_xor(sum, 32);
    const float inv = 1.f / sum;

    // ---- V^T fragments via hardware transpose-read (per-lane addr) ----
    short4v vlo[7], vhi[7];
#pragma unroll
    for (int tau = 0; tau < 7; ++tau) {
      const unsigned va = vbase_addr + tau * 1024;
      asm volatile("ds_read_b64_tr_b16 %0, %1" : "=v"(vlo[tau]) : "v"(va));
      if (tau < 6) {
        asm volatile("ds_read_b64_tr_b16 %0, %1 offset:512"
                     : "=v"(vhi[tau])
                     : "v"(va));
      } else {
        vhi[tau] = (short4v){0, 0, 0, 0};  // slots 208-223: pf is 0 anyway
      }
    }
    asm volatile("s_waitcnt lgkmcnt(0)" ::: "memory");
    __builtin_amdgcn_sched_barrier(0);

    // ---- PV: O^T = sum_tau mfma(V^T frag, P^T frag) ----
    f32x4 oacc = {0.f, 0.f, 0.f, 0.f};
#pragma unroll
    for (int tau = 0; tau < 7; ++tau) {
      short8v pf;
#pragma unroll
      for (int e = 0; e < 4; ++e) pf[e] = (short)f2bf(sim[2 * tau][e]);
#pragma unroll
      for (int e = 0; e < 4; ++e)
        pf[4 + e] =
            (2 * tau + 1 < 13) ? (short)f2bf(sim[2 * tau + 1][e]) : (short)0;
      const short8v vf = __builtin_shufflevector(vlo[tau], vhi[tau], 0, 1, 2,
                                                 3, 4, 5, 6, 7);
      oacc = mfma_bf16(vf, pf, oacc);
    }

    // ---- epilogue: lane holds O^T[c=4*hq+e][qrow]; scale by 1/sum ----
    const int qrow = (qhalf * 2 + q2) * 16 + r;
    const int y = bh * BLK + (qrow >> 3);
    const int xx = bw * BLK + (qrow & 7);
    float* op = out + ((size_t)b * C + head * D + 4 * hq) * HW + y * W + xx;
#pragma unroll
    for (int e = 0; e < 4; ++e) op[(size_t)e * HW] = oacc[e] * inv;
  }
}

extern "C" void kernel_launch(void* const* d_in, const int* in_sizes, int n_in,
                              void* d_out, int out_size, void* d_ws,
                              size_t ws_size, hipStream_t stream) {
  const float* x = (const float*)d_in[0];      // (4, 64, 192, 192)
  const float* w_qkv = (const float*)d_in[1];  // (192, 64)
  const float* rel_h = (const float*)d_in[2];  // (1, 14, 1, 8)
  const float* rel_w = (const float*)d_in[3];  // (1, 1, 14, 8)
  float* out = (float*)d_out;                  // (4, 64, 192, 192)

  unsigned short* qkv = (unsigned short*)d_ws;  // (B, H, W, O) bf16

  qkv_mfma<<<B * HW / 128, 256, 0, stream>>>(x, w_qkv, qkv);
  attn_kernel<<<B * NH * NW, 512, 0, stream>>>(qkv, rel_h, rel_w, out);
}

// Round 9
// 76.885 us; speedup vs baseline: 2.6368x; 2.6368x over previous
//
#include <hip/hip_runtime.h>
#include <hip/hip_bf16.h>

// Problem constants
constexpr int B = 4, C = 64, H = 192, W = 192;
constexpr int HEADS = 4, D = 16;           // d = C/HEADS
constexpr int BLK = 8, HALO = 3, WIN = 14; // WIN = BLK + 2*HALO
constexpr int NH = H / BLK, NW = W / BLK;  // 24 x 24 windows
constexpr int HW = H * W;                  // 36864
constexpr int O = 3 * C;                   // 192 qkv channels

// attn LDS layout (units: shorts) — R6-proven layout (53888 B)
constexpr int K_OFF = 0;                   // K: [208 pixels][8 chunks x 8ch], XOR-swizzled
constexpr int VPLANE = 208 * 16 + 16;      // V plane: [208 slots][16 ch] + pad
constexpr int V_OFF = 208 * 64;            // 13312
constexpr int RH_OFF = V_OFF + 4 * VPLANE; // rel_h bf16 [16][8] (rows >=14 clamped)
constexpr int RW_OFF = RH_OFF + 128;       // rel_w bf16 [16][8]
constexpr int LDS_TOT = RW_OFF + 128;      // 26944 shorts = 53888 B

typedef __attribute__((ext_vector_type(4))) short short4v;
typedef __attribute__((ext_vector_type(8))) short short8v;
typedef __attribute__((ext_vector_type(8))) __bf16 bf16x8;
typedef __attribute__((ext_vector_type(4))) float f32x4;

__device__ inline f32x4 mfma_bf16(short8v a, short8v b, f32x4 c) {
  return __builtin_amdgcn_mfma_f32_16x16x32_bf16(
      __builtin_bit_cast(bf16x8, a), __builtin_bit_cast(bf16x8, b), c, 0, 0, 0);
}

__device__ inline unsigned short f2bf(float f) {
  __bf16 h = (__bf16)f;
  return __builtin_bit_cast(unsigned short, h);
}

// ---------------------------------------------------------------------------
// Kernel 1: qkv projection as MFMA GEMM (unchanged; near HBM floor).
// q rows pre-scaled by d^-0.5 * log2(e) so attention works in exp2 domain.
// ---------------------------------------------------------------------------
__global__ __launch_bounds__(256) void qkv_mfma(
    const float* __restrict__ x, const float* __restrict__ w,
    unsigned short* __restrict__ qkv) {
  __shared__ unsigned short wlds[192 * 64];
  const int tid = threadIdx.x;

  const float4* wf4 = reinterpret_cast<const float4*>(w);
#pragma unroll
  for (int it = 0; it < 12; ++it) {
    const int idx = it * 256 + tid;  // 3072 float4s
    const int o = idx >> 4;
    const int c = (idx & 15) << 2;
    const float4 wv = wf4[idx];
    ushort4 st;
    st.x = f2bf(wv.x);
    st.y = f2bf(wv.y);
    st.z = f2bf(wv.z);
    st.w = f2bf(wv.w);
    const int sw = (((c >> 3) ^ (o & 7)) << 3) + (c & 4);
    *reinterpret_cast<ushort4*>(&wlds[o * 64 + sw]) = st;
  }

  const int wave = tid >> 6, lane = tid & 63;
  const int p = lane & 15, g = lane >> 4;
  const int pix_w = blockIdx.x * 128 + wave * 32;
  const int b = pix_w / HW;
  const int hw = pix_w - b * HW + p;
  const float* xb = x + (size_t)b * C * HW;

  short8v xf[2][2];
#pragma unroll
  for (int pt = 0; pt < 2; ++pt) {
#pragma unroll
    for (int ks = 0; ks < 2; ++ks) {
      unsigned short u[8];
#pragma unroll
      for (int j = 0; j < 8; ++j)
        u[j] = f2bf(xb[(size_t)(ks * 32 + g * 8 + j) * HW + hw + pt * 16]);
      unsigned int pw[4];
#pragma unroll
      for (int e = 0; e < 4; ++e)
        pw[e] = (unsigned int)u[2 * e] | ((unsigned int)u[2 * e + 1] << 16);
      xf[pt][ks] = __builtin_bit_cast(short8v, *reinterpret_cast<uint4*>(pw));
    }
  }
  __syncthreads();

#pragma unroll
  for (int ot = 0; ot < 12; ++ot) {
    short8v af[2];
#pragma unroll
    for (int ks = 0; ks < 2; ++ks)
      af[ks] = *reinterpret_cast<const short8v*>(
          wlds + (ot * 16 + p) * 64 + (((((ks << 2) | g)) ^ (p & 7)) << 3));
    // q pre-scale: d^-0.5 * log2(e) -> attention uses exp2 directly
    const float s = (ot < 4) ? 0.25f * 1.44269504f : 1.0f;
#pragma unroll
    for (int pt = 0; pt < 2; ++pt) {
      f32x4 acc = {0.f, 0.f, 0.f, 0.f};
      acc = mfma_bf16(af[0], xf[pt][0], acc);
      acc = mfma_bf16(af[1], xf[pt][1], acc);
      ushort4 st;
      st.x = f2bf(acc[0] * s);
      st.y = f2bf(acc[1] * s);
      st.z = f2bf(acc[2] * s);
      st.w = f2bf(acc[3] * s);
      *reinterpret_cast<ushort4*>(
          qkv + (size_t)(pix_w + pt * 16 + p) * O + ot * 16 + g * 4) = st;
    }
  }
}

// ---------------------------------------------------------------------------
// Kernel 2: MFMA window attention v6 = R6-proven v3b structure
//   + no softmax max-pass (proven in R7; exp2-domain sims are O(1), fp32-safe)
//   + s_setprio(1) around MFMA/softmax region (T5).
// K full 208 rows (no junk reads), (512,4) launch bounds (no spill pressure —
// R8's 2e31 failure attributed to tr_read-output spill under the 85-VGPR cap).
// ---------------------------------------------------------------------------
__global__ __launch_bounds__(512, 4) void attn_kernel(
    const unsigned short* __restrict__ qkv,
    const float* __restrict__ rel_h, const float* __restrict__ rel_w,
    float* __restrict__ out) {
  __shared__ __align__(16) unsigned short lds[LDS_TOT];

  const int tid = threadIdx.x;
  const int blk = blockIdx.x;
  const int win = (blk & 7) * 288 + (blk >> 3);  // XCD swizzle (2304 % 8 == 0)
  const int b = win / (NH * NW);
  const int wrem = win - b * (NH * NW);
  const int bh = wrem / NW;
  const int bw = wrem - bh * NW;
  const int y0 = bh * BLK - HALO;
  const int x0 = bw * BLK - HALO;

  // ---- rel tables -> bf16 LDS (rows >= 14 clamped to 13) ----
  if (tid < 256) {
    const int i = tid & 127;
    const int rr = i >> 3, cc = i & 7;
    const int rc = (rr < WIN) ? rr : (WIN - 1);
    const float* src = (tid < 128) ? rel_h : rel_w;
    lds[((tid < 128) ? RH_OFF : RW_OFF) + i] = f2bf(src[rc * 8 + cc]);
  }

  // ---- staging phase 1: issue all K/V global loads (T14 split) ----
  // items 0..1663 = K (pixel 0..207, 8 chunks), 1664..3327 = V
  uint4 raw[7];
#pragma unroll
  for (int it = 0; it < 7; ++it) {
    const int item = tid + it * 512;
    const bool isK = item < 1664;
    const int li = isK ? item : item - 1664;
    const int pixel = li >> 3;
    const int g = li & 7;
    const int wy = pixel / WIN;  // up to 14 for pad pixels
    const int wx = pixel - wy * WIN;
    const int y = y0 + wy, xx = x0 + wx;
    const bool inb =
        (item < 3328) & (y >= 0) & (y < H) & (xx >= 0) & (xx < W);
    uint4 rv = make_uint4(0u, 0u, 0u, 0u);
    if (inb)
      rv = *reinterpret_cast<const uint4*>(
          qkv + ((size_t)(b * HW + y * W + xx)) * O + (isK ? C : 2 * C) + g * 8);
    raw[it] = rv;
  }

  // ---- Q fragment prefetch (hq>=2 lanes supply q[0:8]/q[8:16] against the
  //      rel depth slots — no zero select anywhere) ----
  const int lane = tid & 63;
  const int wv = tid >> 6;
  const int head = wv & 3;
  const int qhalf = wv >> 2;
  const int r = lane & 15, hq = lane >> 4;
  short8v qf[2];
#pragma unroll
  for (int q2 = 0; q2 < 2; ++q2) {
    const int qrow = (qhalf * 2 + q2) * 16 + r;
    const int y = bh * BLK + (qrow >> 3);
    const int xx = bw * BLK + (qrow & 7);
    qf[q2] = *reinterpret_cast<const short8v*>(
        qkv + ((size_t)(b * HW + y * W + xx)) * O + head * D + (hq & 1) * 8);
  }

  // ---- staging phase 2: LDS writes (pure copies) ----
#pragma unroll
  for (int it = 0; it < 7; ++it) {
    const int item = tid + it * 512;
    if (item < 3328) {
      const bool isK = item < 1664;
      const int li = isK ? item : item - 1664;
      const int pixel = li >> 3;
      const int g = li & 7;
      if (isK) {
        const int ch = (g ^ pixel) & 7;  // chunk XOR swizzle
        *reinterpret_cast<uint4*>(&lds[K_OFF + pixel * 64 + ch * 8]) = raw[it];
      } else {
        const int hd = g >> 1, c8 = g & 1;
        *reinterpret_cast<uint4*>(
            &lds[V_OFF + hd * VPLANE + pixel * 16 + c8 * 8]) = raw[it];
      }
    }
  }
  __syncthreads();

  // ---- per-lane A-frag LDS offsets (shorts), one per QK tile ----
  // hq<2: K row chunks; hq==2: rel_h[wy]; hq==3: rel_w[wx]
  int koff[13];
#pragma unroll
  for (int t = 0; t < 13; ++t) {
    const int row = 16 * t + r;
    const int wy = row / WIN;
    const int wx = row - wy * WIN;
    const int a_k =
        K_OFF + row * 64 + ((((head << 1) | (hq & 1)) ^ (row & 7)) << 3);
    const int a_rh = RH_OFF + wy * 8;
    const int a_rw = RW_OFF + wx * 8;
    koff[t] = (hq < 2) ? a_k : ((hq == 2) ? a_rh : a_rw);
  }

  // ---- V^T fragments via hardware transpose-read (per-lane addr):
  //      lane l supplies base + 8*l; lane(r,hq) elem j = V[32*tau+4*hq+j][r];
  //      offset:512 gives +16 slots. ----
  const unsigned vbase_addr =
      (unsigned)(unsigned long long)(const void*)&lds[V_OFF + head * VPLANE] +
      (unsigned)(lane * 8);
  short4v vlo[7], vhi[7];
#pragma unroll
  for (int tau = 0; tau < 7; ++tau) {
    const unsigned va = vbase_addr + tau * 1024;
    asm volatile("ds_read_b64_tr_b16 %0, %1" : "=v"(vlo[tau]) : "v"(va));
    if (tau < 6) {
      asm volatile("ds_read_b64_tr_b16 %0, %1 offset:512"
                   : "=v"(vhi[tau])
                   : "v"(va));
    } else {
      vhi[tau] = (short4v){0, 0, 0, 0};  // slots 208-223: pf is 0 anyway
    }
  }
  asm volatile("s_waitcnt lgkmcnt(0)" ::: "memory");
  __builtin_amdgcn_sched_barrier(0);

  __builtin_amdgcn_s_setprio(1);
  for (int q2 = 0; q2 < 2; ++q2) {
    // ---- sim^T tiles: augmented MFMA computes q*(k+rel) ----
    f32x4 sim[13];
#pragma unroll
    for (int t = 0; t < 13; ++t) {
      const short8v kf = *reinterpret_cast<const short8v*>(&lds[koff[t]]);
      f32x4 z4 = {0.f, 0.f, 0.f, 0.f};
      sim[t] = mfma_bf16(kf, qf[q2], z4);
    }

    // ---- softmax, no max-pass (exp2-domain sims are O(1), fp32-safe) ----
    float sum = 0.f;
#pragma unroll
    for (int t = 0; t < 13; ++t) {
#pragma unroll
      for (int e = 0; e < 4; ++e) {
        float p = exp2f(sim[t][e]);
        if (t == 12 && hq >= 1) p = 0.f;  // keys >= 196: pad
        sim[t][e] = p;
        sum += p;
      }
    }
    sum += __shfl_xor(sum, 16);
    sum += __shfl_xor(sum, 32);
    const float inv = 1.f / sum;

    // ---- PV: O^T = sum_tau mfma(V^T frag, P^T frag) ----
    f32x4 oacc = {0.f, 0.f, 0.f, 0.f};
#pragma unroll
    for (int tau = 0; tau < 7; ++tau) {
      short8v pf;
#pragma unroll
      for (int e = 0; e < 4; ++e) pf[e] = (short)f2bf(sim[2 * tau][e]);
#pragma unroll
      for (int e = 0; e < 4; ++e)
        pf[4 + e] =
            (2 * tau + 1 < 13) ? (short)f2bf(sim[2 * tau + 1][e]) : (short)0;
      const short8v vf = __builtin_shufflevector(vlo[tau], vhi[tau], 0, 1, 2,
                                                 3, 4, 5, 6, 7);
      oacc = mfma_bf16(vf, pf, oacc);
    }

    // ---- epilogue: lane holds O^T[c=4*hq+e][qrow]; scale by 1/sum ----
    const int qrow = (qhalf * 2 + q2) * 16 + r;
    const int y = bh * BLK + (qrow >> 3);
    const int xx = bw * BLK + (qrow & 7);
    float* op = out + ((size_t)b * C + head * D + 4 * hq) * HW + y * W + xx;
#pragma unroll
    for (int e = 0; e < 4; ++e) op[(size_t)e * HW] = oacc[e] * inv;
  }
  __builtin_amdgcn_s_setprio(0);
}

extern "C" void kernel_launch(void* const* d_in, const int* in_sizes, int n_in,
                              void* d_out, int out_size, void* d_ws,
                              size_t ws_size, hipStream_t stream) {
  const float* x = (const float*)d_in[0];      // (4, 64, 192, 192)
  const float* w_qkv = (const float*)d_in[1];  // (192, 64)
  const float* rel_h = (const float*)d_in[2];  // (1, 14, 1, 8)
  const float* rel_w = (const float*)d_in[3];  // (1, 1, 14, 8)
  float* out = (float*)d_out;                  // (4, 64, 192, 192)

  unsigned short* qkv = (unsigned short*)d_ws;  // (B, H, W, O) bf16

  qkv_mfma<<<B * HW / 128, 256, 0, stream>>>(x, w_qkv, qkv);
  attn_kernel<<<B * NH * NW, 512, 0, stream>>>(qkv, rel_h, rel_w, out);
}

// Round 10
// 63.290 us; speedup vs baseline: 3.2032x; 1.2148x over previous
//
#include <hip/hip_runtime.h>
#include <hip/hip_bf16.h>

// Problem constants
constexpr int B = 4, C = 64, H = 192, W = 192;
constexpr int HEADS = 4, D = 16;           // d = C/HEADS
constexpr int BLK = 8, HALO = 3, WIN = 14; // WIN = BLK + 2*HALO
constexpr int NH = H / BLK, NW = W / BLK;  // 24 x 24 windows
constexpr int HW = H * W;                  // 36864
constexpr int O = 3 * C;                   // 192 qkv channels

// attn LDS layout (units: shorts) — R6/R9-proven layout (53888 B)
constexpr int K_OFF = 0;                   // K: [208 pixels][8 chunks x 8ch], XOR-swizzled
constexpr int VPLANE = 208 * 16 + 16;      // V plane: [208 slots][16 ch] + pad
constexpr int V_OFF = 208 * 64;            // 13312
constexpr int RH_OFF = V_OFF + 4 * VPLANE; // rel_h bf16 [16][8] (rows >=14 clamped)
constexpr int RW_OFF = RH_OFF + 128;       // rel_w bf16 [16][8]
constexpr int LDS_TOT = RW_OFF + 128;      // 26944 shorts = 53888 B

typedef __attribute__((ext_vector_type(4))) short short4v;
typedef __attribute__((ext_vector_type(8))) short short8v;
typedef __attribute__((ext_vector_type(8))) __bf16 bf16x8;
typedef __attribute__((ext_vector_type(4))) float f32x4;

__device__ inline f32x4 mfma_bf16(short8v a, short8v b, f32x4 c) {
  return __builtin_amdgcn_mfma_f32_16x16x32_bf16(
      __builtin_bit_cast(bf16x8, a), __builtin_bit_cast(bf16x8, b), c, 0, 0, 0);
}

__device__ inline unsigned short f2bf(float f) {
  __bf16 h = (__bf16)f;
  return __builtin_bit_cast(unsigned short, h);
}

// packed bf16 pair: lo = bf16(a), hi = bf16(b) — single HW instr (T12)
__device__ inline unsigned cvt_pk_bf16(float a, float b) {
  unsigned r;
  asm("v_cvt_pk_bf16_f32 %0, %1, %2" : "=v"(r) : "v"(a), "v"(b));
  return r;
}

// ---------------------------------------------------------------------------
// Kernel 1: qkv projection as MFMA GEMM (unchanged; near HBM floor).
// q rows pre-scaled by d^-0.5 * log2(e) so attention works in exp2 domain.
// ---------------------------------------------------------------------------
__global__ __launch_bounds__(256) void qkv_mfma(
    const float* __restrict__ x, const float* __restrict__ w,
    unsigned short* __restrict__ qkv) {
  __shared__ unsigned short wlds[192 * 64];
  const int tid = threadIdx.x;

  const float4* wf4 = reinterpret_cast<const float4*>(w);
#pragma unroll
  for (int it = 0; it < 12; ++it) {
    const int idx = it * 256 + tid;  // 3072 float4s
    const int o = idx >> 4;
    const int c = (idx & 15) << 2;
    const float4 wv = wf4[idx];
    ushort4 st;
    st.x = f2bf(wv.x);
    st.y = f2bf(wv.y);
    st.z = f2bf(wv.z);
    st.w = f2bf(wv.w);
    const int sw = (((c >> 3) ^ (o & 7)) << 3) + (c & 4);
    *reinterpret_cast<ushort4*>(&wlds[o * 64 + sw]) = st;
  }

  const int wave = tid >> 6, lane = tid & 63;
  const int p = lane & 15, g = lane >> 4;
  const int pix_w = blockIdx.x * 128 + wave * 32;
  const int b = pix_w / HW;
  const int hw = pix_w - b * HW + p;
  const float* xb = x + (size_t)b * C * HW;

  short8v xf[2][2];
#pragma unroll
  for (int pt = 0; pt < 2; ++pt) {
#pragma unroll
    for (int ks = 0; ks < 2; ++ks) {
      unsigned short u[8];
#pragma unroll
      for (int j = 0; j < 8; ++j)
        u[j] = f2bf(xb[(size_t)(ks * 32 + g * 8 + j) * HW + hw + pt * 16]);
      unsigned int pw[4];
#pragma unroll
      for (int e = 0; e < 4; ++e)
        pw[e] = (unsigned int)u[2 * e] | ((unsigned int)u[2 * e + 1] << 16);
      xf[pt][ks] = __builtin_bit_cast(short8v, *reinterpret_cast<uint4*>(pw));
    }
  }
  __syncthreads();

#pragma unroll
  for (int ot = 0; ot < 12; ++ot) {
    short8v af[2];
#pragma unroll
    for (int ks = 0; ks < 2; ++ks)
      af[ks] = *reinterpret_cast<const short8v*>(
          wlds + (ot * 16 + p) * 64 + (((((ks << 2) | g)) ^ (p & 7)) << 3));
    // q pre-scale: d^-0.5 * log2(e) -> attention uses exp2 directly
    const float s = (ot < 4) ? 0.25f * 1.44269504f : 1.0f;
#pragma unroll
    for (int pt = 0; pt < 2; ++pt) {
      f32x4 acc = {0.f, 0.f, 0.f, 0.f};
      acc = mfma_bf16(af[0], xf[pt][0], acc);
      acc = mfma_bf16(af[1], xf[pt][1], acc);
      ushort4 st;
      st.x = f2bf(acc[0] * s);
      st.y = f2bf(acc[1] * s);
      st.z = f2bf(acc[2] * s);
      st.w = f2bf(acc[3] * s);
      *reinterpret_cast<ushort4*>(
          qkv + (size_t)(pix_w + pt * 16 + p) * O + ot * 16 + g * 4) = st;
    }
  }
}

// ---------------------------------------------------------------------------
// Kernel 2: MFMA window attention v7 = R9 skeleton with the q2 pair fused
// into one streaming pass (enabled by no-max-pass softmax):
//   per tile t: one kf ds_read -> 2 MFMAs (q2=0,1) -> exp2 -> cvt_pk bf16;
//   per tile-pair tau: 2 PV MFMAs accumulate. No sim array, pf transient.
// kf reads halve; QK/PV MFMAs form 2 independent chains; v_cvt_pk_bf16_f32
// and __builtin_amdgcn_exp2f cut VALU glue.
// ---------------------------------------------------------------------------
__global__ __launch_bounds__(512, 4) void attn_kernel(
    const unsigned short* __restrict__ qkv,
    const float* __restrict__ rel_h, const float* __restrict__ rel_w,
    float* __restrict__ out) {
  __shared__ __align__(16) unsigned short lds[LDS_TOT];

  const int tid = threadIdx.x;
  const int blk = blockIdx.x;
  const int win = (blk & 7) * 288 + (blk >> 3);  // XCD swizzle (2304 % 8 == 0)
  const int b = win / (NH * NW);
  const int wrem = win - b * (NH * NW);
  const int bh = wrem / NW;
  const int bw = wrem - bh * NW;
  const int y0 = bh * BLK - HALO;
  const int x0 = bw * BLK - HALO;

  // ---- rel tables -> bf16 LDS (rows >= 14 clamped to 13) ----
  if (tid < 256) {
    const int i = tid & 127;
    const int rr = i >> 3, cc = i & 7;
    const int rc = (rr < WIN) ? rr : (WIN - 1);
    const float* src = (tid < 128) ? rel_h : rel_w;
    lds[((tid < 128) ? RH_OFF : RW_OFF) + i] = f2bf(src[rc * 8 + cc]);
  }

  // ---- staging phase 1: issue all K/V global loads (T14 split) ----
  // items 0..1663 = K (pixel 0..207, 8 chunks), 1664..3327 = V
  uint4 raw[7];
#pragma unroll
  for (int it = 0; it < 7; ++it) {
    const int item = tid + it * 512;
    const bool isK = item < 1664;
    const int li = isK ? item : item - 1664;
    const int pixel = li >> 3;
    const int g = li & 7;
    const int wy = pixel / WIN;  // up to 14 for pad pixels
    const int wx = pixel - wy * WIN;
    const int y = y0 + wy, xx = x0 + wx;
    const bool inb = (item < 3328) & ((unsigned)y < (unsigned)H) &
                     ((unsigned)xx < (unsigned)W);
    uint4 rv = make_uint4(0u, 0u, 0u, 0u);
    if (inb)
      rv = *reinterpret_cast<const uint4*>(
          qkv + ((size_t)(b * HW + y * W + xx)) * O + (isK ? C : 2 * C) + g * 8);
    raw[it] = rv;
  }

  // ---- Q fragment prefetch (hq>=2 lanes supply q[0:8]/q[8:16] against the
  //      rel depth slots — no zero select anywhere) ----
  const int lane = tid & 63;
  const int wv = tid >> 6;
  const int head = wv & 3;
  const int qhalf = wv >> 2;
  const int r = lane & 15, hq = lane >> 4;
  const int qrow0 = qhalf * 32 + r;  // q2=0 row; q2=1 row = +16
  short8v qf0, qf1;
  {
    const int y = bh * BLK + (qrow0 >> 3);
    const int xx = bw * BLK + (qrow0 & 7);
    qf0 = *reinterpret_cast<const short8v*>(
        qkv + ((size_t)(b * HW + y * W + xx)) * O + head * D + (hq & 1) * 8);
    const int qrow1 = qrow0 + 16;
    const int y1 = bh * BLK + (qrow1 >> 3);
    const int xx1 = bw * BLK + (qrow1 & 7);
    qf1 = *reinterpret_cast<const short8v*>(
        qkv + ((size_t)(b * HW + y1 * W + xx1)) * O + head * D + (hq & 1) * 8);
  }

  // ---- staging phase 2: LDS writes (pure copies) ----
#pragma unroll
  for (int it = 0; it < 7; ++it) {
    const int item = tid + it * 512;
    if (item < 3328) {
      const bool isK = item < 1664;
      const int li = isK ? item : item - 1664;
      const int pixel = li >> 3;
      const int g = li & 7;
      if (isK) {
        const int ch = (g ^ pixel) & 7;  // chunk XOR swizzle
        *reinterpret_cast<uint4*>(&lds[K_OFF + pixel * 64 + ch * 8]) = raw[it];
      } else {
        const int hd = g >> 1, c8 = g & 1;
        *reinterpret_cast<uint4*>(
            &lds[V_OFF + hd * VPLANE + pixel * 16 + c8 * 8]) = raw[it];
      }
    }
  }
  __syncthreads();

  // ---- per-lane A-frag LDS offsets (shorts), one per QK tile ----
  // hq<2: K row chunks; hq==2: rel_h[wy]; hq==3: rel_w[wx]
  int koff[13];
#pragma unroll
  for (int t = 0; t < 13; ++t) {
    const int row = 16 * t + r;
    const int wy = row / WIN;
    const int wx = row - wy * WIN;
    const int a_k =
        K_OFF + row * 64 + ((((head << 1) | (hq & 1)) ^ (row & 7)) << 3);
    const int a_rh = RH_OFF + wy * 8;
    const int a_rw = RW_OFF + wx * 8;
    koff[t] = (hq < 2) ? a_k : ((hq == 2) ? a_rh : a_rw);
  }

  // ---- V^T fragments via hardware transpose-read (per-lane addr):
  //      lane l supplies base + 8*l; lane(r,hq) elem j = V[32*tau+4*hq+j][r];
  //      offset:512 gives +16 slots. ----
  const unsigned vbase_addr =
      (unsigned)(unsigned long long)(const void*)&lds[V_OFF + head * VPLANE] +
      (unsigned)(lane * 8);
  short4v vlo[7], vhi[7];
#pragma unroll
  for (int tau = 0; tau < 7; ++tau) {
    const unsigned va = vbase_addr + tau * 1024;
    asm volatile("ds_read_b64_tr_b16 %0, %1" : "=v"(vlo[tau]) : "v"(va));
    if (tau < 6) {
      asm volatile("ds_read_b64_tr_b16 %0, %1 offset:512"
                   : "=v"(vhi[tau])
                   : "v"(va));
    } else {
      vhi[tau] = (short4v){0, 0, 0, 0};  // slots 208-223: pf is 0 anyway
    }
  }
  asm volatile("s_waitcnt lgkmcnt(0)" ::: "memory");
  __builtin_amdgcn_sched_barrier(0);

  __builtin_amdgcn_s_setprio(1);

  // ---- fused streaming pass: QK -> exp2 -> pack -> PV, both q2 at once ----
  f32x4 oacc0 = {0.f, 0.f, 0.f, 0.f}, oacc1 = {0.f, 0.f, 0.f, 0.f};
  float sum0 = 0.f, sum1 = 0.f;
#pragma unroll
  for (int tau = 0; tau < 7; ++tau) {
    unsigned pw0[4], pw1[4];
#pragma unroll
    for (int half = 0; half < 2; ++half) {
      const int t = 2 * tau + half;
      if (t < 13) {
        const short8v kf = *reinterpret_cast<const short8v*>(&lds[koff[t]]);
        const f32x4 z4 = {0.f, 0.f, 0.f, 0.f};
        const f32x4 s0 = mfma_bf16(kf, qf0, z4);
        const f32x4 s1 = mfma_bf16(kf, qf1, z4);
        float p0e[4], p1e[4];
#pragma unroll
        for (int e = 0; e < 4; ++e) {
          float pa = __builtin_amdgcn_exp2f(s0[e]);
          float pb = __builtin_amdgcn_exp2f(s1[e]);
          if (t == 12 && hq >= 1) {  // keys >= 196: pad
            pa = 0.f;
            pb = 0.f;
          }
          sum0 += pa;
          sum1 += pb;
          p0e[e] = pa;
          p1e[e] = pb;
        }
        pw0[half * 2 + 0] = cvt_pk_bf16(p0e[0], p0e[1]);
        pw0[half * 2 + 1] = cvt_pk_bf16(p0e[2], p0e[3]);
        pw1[half * 2 + 0] = cvt_pk_bf16(p1e[0], p1e[1]);
        pw1[half * 2 + 1] = cvt_pk_bf16(p1e[2], p1e[3]);
      } else {  // tau == 6 high half: keys 208-223 virtual
        pw0[2] = 0u;
        pw0[3] = 0u;
        pw1[2] = 0u;
        pw1[3] = 0u;
      }
    }
    const short8v vf =
        __builtin_shufflevector(vlo[tau], vhi[tau], 0, 1, 2, 3, 4, 5, 6, 7);
    const uint4 u0 = make_uint4(pw0[0], pw0[1], pw0[2], pw0[3]);
    const uint4 u1 = make_uint4(pw1[0], pw1[1], pw1[2], pw1[3]);
    oacc0 = mfma_bf16(vf, __builtin_bit_cast(short8v, u0), oacc0);
    oacc1 = mfma_bf16(vf, __builtin_bit_cast(short8v, u1), oacc1);
  }

  // ---- softmax denominators (row spread across lane groups ^16, ^32) ----
  sum0 += __shfl_xor(sum0, 16);
  sum0 += __shfl_xor(sum0, 32);
  sum1 += __shfl_xor(sum1, 16);
  sum1 += __shfl_xor(sum1, 32);
  const float inv0 = 1.f / sum0;
  const float inv1 = 1.f / sum1;

  // ---- epilogue: lane holds O^T[c=4*hq+e][qrow]; scale by 1/sum ----
  {
    const int y = bh * BLK + (qrow0 >> 3);
    const int xx = bw * BLK + (qrow0 & 7);
    float* op = out + ((size_t)b * C + head * D + 4 * hq) * HW + y * W + xx;
#pragma unroll
    for (int e = 0; e < 4; ++e) op[(size_t)e * HW] = oacc0[e] * inv0;
  }
  {
    const int qrow1 = qrow0 + 16;
    const int y = bh * BLK + (qrow1 >> 3);
    const int xx = bw * BLK + (qrow1 & 7);
    float* op = out + ((size_t)b * C + head * D + 4 * hq) * HW + y * W + xx;
#pragma unroll
    for (int e = 0; e < 4; ++e) op[(size_t)e * HW] = oacc1[e] * inv1;
  }
  __builtin_amdgcn_s_setprio(0);
}

extern "C" void kernel_launch(void* const* d_in, const int* in_sizes, int n_in,
                              void* d_out, int out_size, void* d_ws,
                              size_t ws_size, hipStream_t stream) {
  const float* x = (const float*)d_in[0];      // (4, 64, 192, 192)
  const float* w_qkv = (const float*)d_in[1];  // (192, 64)
  const float* rel_h = (const float*)d_in[2];  // (1, 14, 1, 8)
  const float* rel_w = (const float*)d_in[3];  // (1, 1, 14, 8)
  float* out = (float*)d_out;                  // (4, 64, 192, 192)

  unsigned short* qkv = (unsigned short*)d_ws;  // (B, H, W, O) bf16

  qkv_mfma<<<B * HW / 128, 256, 0, stream>>>(x, w_qkv, qkv);
  attn_kernel<<<B * NH * NW, 512, 0, stream>>>(qkv, rel_h, rel_w, out);
}